// Round 8
// baseline (846.483 us; speedup 1.0000x reference)
//
#include <hip/hip_runtime.h>
#include <hip/hip_bf16.h>
#include <math.h>

// Problem constants
#define BQ   16384        // windows
#define CH   512
#define NH   8
#define HID  2048
#define NTOK (BQ*4)       // 65536 rows

using bf16 = __hip_bfloat16;
typedef __bf16 bf16x8 __attribute__((ext_vector_type(8)));
typedef float  f32x4  __attribute__((ext_vector_type(4)));

__device__ __forceinline__ void gload16(const void* g, void* l) {
    __builtin_amdgcn_global_load_lds(
        (const __attribute__((address_space(1))) void*)g,
        (__attribute__((address_space(3))) void*)l, 16, 0, 0);
}

// ---------------- weight pack: fp32 row-major [N][K] -> staged-order bf16 ----
// 16KB slab per (colblock cb of 256 rows-of-W, K-slice s of 32):
//   elem addr = (cb*NSk + s)*8192 + w*1024 + jj*512 + l*8    (w<8, jj<2, l<64)
//   content   = W[cb*256 + w*32 + jj*16 + (l>>2)][s*32 + ((l&3)^((l>>3)&3))*8 ..+8]
// GEMM B-staging reads contiguous 1KB per gload_lds; LDS image matches the
// XOR-swizzled slot layout the fragment reads expect.
__global__ __launch_bounds__(256) void packw(const float* __restrict__ Wsrc,
                                             bf16* __restrict__ out, int N, int K) {
    int q = blockIdx.x * 256 + threadIdx.x;      // 16B-chunk id
    int NSk = K >> 5;
    int total = (N >> 8) * NSk * 1024;
    if (q >= total) return;
    int l  = q & 63;
    int jj = (q >> 6) & 1;
    int w  = (q >> 7) & 7;
    int s  = (q >> 10) % NSk;
    int cb = q / (NSk * 1024);
    int row = cb * 256 + w * 32 + jj * 16 + (l >> 2);
    int k   = s * 32 + ((l & 3) ^ ((l >> 3) & 3)) * 8;
    const float* src = Wsrc + (size_t)row * K + k;
    float4 v0 = *(const float4*)src;
    float4 v1 = *(const float4*)(src + 4);
    __align__(16) bf16 t[8];
    t[0] = __float2bfloat16(v0.x); t[1] = __float2bfloat16(v0.y);
    t[2] = __float2bfloat16(v0.z); t[3] = __float2bfloat16(v0.w);
    t[4] = __float2bfloat16(v1.x); t[5] = __float2bfloat16(v1.y);
    t[6] = __float2bfloat16(v1.z); t[7] = __float2bfloat16(v1.w);
    *(uint4*)&out[(size_t)q * 8] = *(const uint4*)t;
}

// ---------------- LayerNorm (fp32 in, bf16 out), one wave per row ----------------
__global__ __launch_bounds__(256) void ln_kernel(const float* __restrict__ x,
                                                 const float* __restrict__ g,
                                                 const float* __restrict__ b,
                                                 bf16* __restrict__ out) {
    int row  = blockIdx.x * 4 + (threadIdx.x >> 6);
    int lane = threadIdx.x & 63;
    const float* xr = x + (size_t)row * CH;
    int c0 = lane * 8;
    float4 v0 = *(const float4*)&xr[c0];
    float4 v1 = *(const float4*)&xr[c0 + 4];
    float s  = v0.x + v0.y + v0.z + v0.w + v1.x + v1.y + v1.z + v1.w;
    float sq = v0.x*v0.x + v0.y*v0.y + v0.z*v0.z + v0.w*v0.w
             + v1.x*v1.x + v1.y*v1.y + v1.z*v1.z + v1.w*v1.w;
#pragma unroll
    for (int off = 32; off >= 1; off >>= 1) {
        s  += __shfl_xor(s,  off, 64);
        sq += __shfl_xor(sq, off, 64);
    }
    float mu  = s * (1.0f / CH);
    float var = sq * (1.0f / CH) - mu * mu;
    float rs  = rsqrtf(var + 1e-5f);
    float4 g0 = *(const float4*)&g[c0];
    float4 g1 = *(const float4*)&g[c0 + 4];
    float4 b0 = *(const float4*)&b[c0];
    float4 b1 = *(const float4*)&b[c0 + 4];
    __align__(16) bf16 t[8];
    t[0] = __float2bfloat16((v0.x - mu) * rs * g0.x + b0.x);
    t[1] = __float2bfloat16((v0.y - mu) * rs * g0.y + b0.y);
    t[2] = __float2bfloat16((v0.z - mu) * rs * g0.z + b0.z);
    t[3] = __float2bfloat16((v0.w - mu) * rs * g0.w + b0.w);
    t[4] = __float2bfloat16((v1.x - mu) * rs * g1.x + b1.x);
    t[5] = __float2bfloat16((v1.y - mu) * rs * g1.y + b1.y);
    t[6] = __float2bfloat16((v1.z - mu) * rs * g1.z + b1.z);
    t[7] = __float2bfloat16((v1.w - mu) * rs * g1.w + b1.w);
    *(uint4*)&out[(size_t)row * CH + c0] = *(const uint4*)t;
}

// ---------------- GEMM 256x256, 8-phase counted-vmcnt (m201-style, rebuilt) ----
// C[M,N] = A[M,K] * B[N,K]^T.  Ring-4 LDS of K-32 slices (32KB: A16|B16).
// 8 waves (2M x 4N), wave tile 128x64.  Per slice: 2 phases of 16 MFMA.
//   PhA(s): vmcnt(4) [retire slot s+1]; s_barrier; { ds_read av/b01(s+1) |
//           stageA(s+3) | setprio(1) 16 MFMA(s,n01) setprio(0) }  (compiler-interleaved)
//   PhB(s): s_barrier; { ds_read b23(s+1) | stageB(s+3) | 16 MFMA(s,n23) }
// vmcnt never 0 in main loop (2 slices in flight); NO sched_barrier (m141),
// NO manual lgkmcnt (compiler tracks C++ ds_read->MFMA deps).
// WAR: stage targets slot s+3 == s-1, whose readers retired >=2 barriers ago;
// cross-wave slice validity = per-wave vmcnt(4) BEFORE the shared barrier.
// Register banks statically named (rule #20).  launch_bounds(512,2) REQUIRED
// (round 5: without it -> 64 VGPR alloc -> acc spills -> 11GB scratch traffic).
template<int EPI>
__global__ __launch_bounds__(512, 2)
void gemm8p(const bf16* __restrict__ A, const bf16* __restrict__ Bp,
            int M, int N, int K, int nbx,
            const float* __restrict__ bias,
            const float* resid, float* outF, bf16* __restrict__ outB) {
    __shared__ __align__(16) char lds[131072];
    const int tid  = threadIdx.x;
    const int w    = tid >> 6;     // wave 0..7
    const int lane = tid & 63;

    // bijective XCD swizzle (gridDim.x % 8 == 0 for all our shapes)
    const int nb  = gridDim.x;
    const int id  = blockIdx.x;
    const int swz = (id & 7) * (nb >> 3) + (id >> 3);
    const int bx  = swz % nbx, by = swz / nbx;
    const int bm = by * 256, bn = bx * 256;
    const int wr = w >> 2;         // 0..1  (M half)
    const int wc = w & 3;          // 0..3  (N quarter)
    const int NSk = K >> 5;        // K/32 slices (16 or 64; even)

    // A staging (strided rows, pre-swizzled k-part)
    const int rl  = lane >> 2;
    const int kpe = ((lane & 3) ^ ((lane >> 3) & 3)) * 8;
    const bf16* gA0 = A + (size_t)(bm + w * 32 + rl) * K + kpe;
    const bf16* gA1 = gA0 + (size_t)16 * K;
    // B staging (packed, contiguous 1KB per load)
    const bf16* gB = Bp + (size_t)(bn >> 8) * NSk * 8192 + w * 1024 + lane * 8;

    // fragment read offsets (bytes) within a slot; same XOR on the read side
    const int kslot = ((lane >> 4) ^ ((lane >> 1) & 3));
    const int aoff = (wr * 128 + (lane & 15)) * 64 + kslot * 16;
    const int boff = 16384 + (wc * 64 + (lane & 15)) * 64 + kslot * 16;

    f32x4 acc[8][4] = {};
    bf16x8 av0[8], av1[8], b01_0[2], b01_1[2], b23_0[2], b23_1[2];

    auto stageA = [&](int s) {
        char* base = (char*)lds + (s & 3) * 32768;
        gload16(gA0 + (size_t)s * 32, base + w * 2048);
        gload16(gA1 + (size_t)s * 32, base + w * 2048 + 1024);
    };
    auto stageB = [&](int s) {
        char* base = (char*)lds + (s & 3) * 32768;
        gload16(gB + (size_t)s * 8192,       base + 16384 + w * 2048);
        gload16(gB + (size_t)s * 8192 + 512, base + 16384 + w * 2048 + 1024);
    };

#define RD_AV(AV, SLOT) { const char* _b = (const char*)lds + (size_t)((SLOT) & 3) * 32768; \
    _Pragma("unroll") for (int _m = 0; _m < 8; ++_m)                                         \
        AV[_m] = *(const bf16x8*)(_b + aoff + _m * 1024); }
#define RD_B2(BV, SLOT, OFF) { const char* _b = (const char*)lds + (size_t)((SLOT) & 3) * 32768; \
    BV[0] = *(const bf16x8*)(_b + boff + (OFF));                                                 \
    BV[1] = *(const bf16x8*)(_b + boff + (OFF) + 1024); }
#define MF16(AV, BV, N0) { __builtin_amdgcn_s_setprio(1);                                    \
    _Pragma("unroll") for (int _m = 0; _m < 8; ++_m) {                                       \
        acc[_m][N0]     = __builtin_amdgcn_mfma_f32_16x16x32_bf16(AV[_m], BV[0], acc[_m][N0],     0, 0, 0); \
        acc[_m][N0 + 1] = __builtin_amdgcn_mfma_f32_16x16x32_bf16(AV[_m], BV[1], acc[_m][N0 + 1], 0, 0, 0); } \
    __builtin_amdgcn_s_setprio(0); }
#define WAITV(n) asm volatile("s_waitcnt vmcnt(" #n ")" ::: "memory")
#define SBAR()   __builtin_amdgcn_s_barrier()

    // prologue: fill ring slots 0..2 (12 loads), read slice 0 into bank 0
    stageA(0); stageB(0); stageA(1); stageB(1); stageA(2); stageB(2);
    WAITV(8);            // slice 0 landed (own loads); barrier globalizes
    SBAR();
    RD_AV(av0, 0); RD_B2(b01_0, 0, 0); RD_B2(b23_0, 0, 2048);

    // main loop: pairs of slices (even: bank0, odd: bank1)
    for (int s = 0; s < NSk - 2; s += 2) {
        // slice s (bank0)  — PhA
        WAITV(4); SBAR();
        RD_AV(av1, s + 1); RD_B2(b01_1, s + 1, 0);
        if (s + 3 < NSk) stageA(s + 3);
        MF16(av0, b01_0, 0);
        // PhB
        SBAR();
        RD_B2(b23_1, s + 1, 2048);
        if (s + 3 < NSk) stageB(s + 3);
        MF16(av0, b23_0, 2);
        // slice s+1 (bank1) — PhA
        WAITV(4); SBAR();
        RD_AV(av0, s + 2); RD_B2(b01_0, s + 2, 0);
        if (s + 4 < NSk) stageA(s + 4);
        MF16(av1, b01_1, 0);
        // PhB
        SBAR();
        RD_B2(b23_0, s + 2, 2048);
        if (s + 4 < NSk) stageB(s + 4);
        MF16(av1, b23_1, 2);
    }
    // tail: slice NSk-2 (bank0) — drain remaining slot NSk-1
    WAITV(0); SBAR();
    RD_AV(av1, NSk - 1); RD_B2(b01_1, NSk - 1, 0);
    MF16(av0, b01_0, 0);
    SBAR();
    RD_B2(b23_1, NSk - 1, 2048);
    MF16(av0, b23_0, 2);
    // slice NSk-1 (bank1): register-only
    MF16(av1, b01_1, 0);
    MF16(av1, b23_1, 2);
#undef RD_AV
#undef RD_B2
#undef MF16
#undef WAITV
#undef SBAR

    // epilogue: frag (m,n): row = wr*128 + m*16 + (lane>>4)*4 + r, col = wc*64 + n*16 + (lane&15)
    const int erow0 = bm + wr * 128 + (lane >> 4) * 4;
    const int ecol0 = bn + wc * 64 + (lane & 15);
#pragma unroll
    for (int m = 0; m < 8; ++m) {
#pragma unroll
        for (int n = 0; n < 4; ++n) {
            int col = ecol0 + n * 16;
#pragma unroll
            for (int r = 0; r < 4; ++r) {
                int row = erow0 + m * 16 + r;
                size_t idx = (size_t)row * N + col;
                float v = acc[m][n][r];
                if (EPI == 0) {
                    outB[idx] = __float2bfloat16(v);
                } else if (EPI == 1) {
                    outF[idx] = v + bias[col] + resid[idx];
                } else {
                    // tanh-form GELU (|err| vs exact erf-GELU ~3e-4 << bf16 ulp)
                    float t = v + bias[col];
                    float u = 0.7978845608f * t * (1.0f + 0.044715f * t * t);
                    float e = __expf(2.0f * u);
                    float th = 1.0f - 2.0f / (e + 1.0f);   // inf-safe
                    outB[idx] = __float2bfloat16(0.5f * t * (1.0f + th));
                }
            }
        }
    }
}

// ---------------- windowed attention: one block per window ----------------
__global__ __launch_bounds__(256)
void attn_kernel(const bf16* __restrict__ qkv, const float* __restrict__ rpb,
                 bf16* __restrict__ o) {
    __shared__ __align__(16) bf16 sT[4 * 1536];
    __shared__ float sS[NH][4][4];
    __shared__ float sP[NH][4][4];
    int b   = blockIdx.x;
    int tid = threadIdx.x;
    const bf16* src = qkv + (size_t)b * (4 * 1536);
#pragma unroll
    for (int it = 0; it < 3; ++it) {
        int e = (it * 256 + tid) * 8;
        *(uint4*)&sT[e] = *(const uint4*)&src[e];
    }
    __syncthreads();
    if (tid < 128) {
        int h = tid >> 4, i = (tid >> 2) & 3, j = tid & 3;
        const bf16* q = &sT[i * 1536 + h * 64];
        const bf16* k = &sT[j * 1536 + 512 + h * 64];
        float acc = 0.f;
#pragma unroll
        for (int d = 0; d < 64; ++d)
            acc += __bfloat162float(q[d]) * __bfloat162float(k[d]);
        int rel = (((i >> 1) - (j >> 1)) + 1) * 3 + (((i & 1) - (j & 1)) + 1);
        sS[h][i][j] = acc * 0.125f + rpb[rel * NH + h];
    }
    __syncthreads();
    if (tid < 32) {
        int h = tid >> 2, i = tid & 3;
        float s0 = sS[h][i][0], s1 = sS[h][i][1], s2 = sS[h][i][2], s3 = sS[h][i][3];
        float mx = fmaxf(fmaxf(s0, s1), fmaxf(s2, s3));
        float e0 = expf(s0 - mx), e1 = expf(s1 - mx), e2 = expf(s2 - mx), e3 = expf(s3 - mx);
        float inv = 1.f / (e0 + e1 + e2 + e3);
        sP[h][i][0] = e0 * inv; sP[h][i][1] = e1 * inv;
        sP[h][i][2] = e2 * inv; sP[h][i][3] = e3 * inv;
    }
    __syncthreads();
    {
        int h = tid >> 5, tl = tid & 31;
        int d = tl * 2;
        const bf16* v = &sT[1024 + h * 64 + d];
#pragma unroll
        for (int i = 0; i < 4; ++i) {
            float p0 = sP[h][i][0], p1 = sP[h][i][1], p2 = sP[h][i][2], p3 = sP[h][i][3];
            float o0 = p0 * __bfloat162float(v[0])        + p1 * __bfloat162float(v[1536])
                     + p2 * __bfloat162float(v[2 * 1536]) + p3 * __bfloat162float(v[3 * 1536]);
            float o1 = p0 * __bfloat162float(v[1])            + p1 * __bfloat162float(v[1536 + 1])
                     + p2 * __bfloat162float(v[2 * 1536 + 1]) + p3 * __bfloat162float(v[3 * 1536 + 1]);
            __hip_bfloat162 pr;
            pr.x = __float2bfloat16(o0);
            pr.y = __float2bfloat16(o1);
            *(__hip_bfloat162*)&o[(size_t)(b * 4 + i) * CH + h * 64 + d] = pr;
        }
    }
}

extern "C" void kernel_launch(void* const* d_in, const int* in_sizes, int n_in,
                              void* d_out, int out_size, void* d_ws, size_t ws_size,
                              hipStream_t stream) {
    const float* x      = (const float*)d_in[0];
    const float* ln_g   = (const float*)d_in[1];
    const float* ln_b   = (const float*)d_in[2];
    const float* qkv_w  = (const float*)d_in[3];
    const float* proj_w = (const float*)d_in[4];
    const float* proj_b = (const float*)d_in[5];
    const float* rpb    = (const float*)d_in[6];
    const float* fc1_w  = (const float*)d_in[7];
    const float* fc1_b  = (const float*)d_in[8];
    const float* fc2_w  = (const float*)d_in[9];
    const float* fc2_b  = (const float*)d_in[10];
    float* out = (float*)d_out;

    // workspace layout (16B aligned throughout)
    char* ws = (char*)d_ws;
    bf16* wQKV  = (bf16*)ws;  ws += (size_t)1536 * 512 * 2;   // packed
    bf16* wPROJ = (bf16*)ws;  ws += (size_t)512  * 512 * 2;
    bf16* wFC1  = (bf16*)ws;  ws += (size_t)2048 * 512 * 2;
    bf16* wFC2  = (bf16*)ws;  ws += (size_t)512 * 2048 * 2;
    bf16* hA    = (bf16*)ws;  ws += (size_t)NTOK * 512 * 2;   // 64 MB: h_ln -> o -> h2
    bf16* big   = (bf16*)ws;                                  // 256 MB: qkv -> fc1 out
    const size_t needed = 6291456ull + 67108864ull + 268435456ull;
    if (ws_size < needed) return;

    // weight packing (fp32 -> staged-order bf16, 256-row col-blocks)
    packw<<<384, 256, 0, stream>>>(qkv_w,  wQKV, 1536, 512);
    packw<<<128, 256, 0, stream>>>(proj_w, wPROJ, 512, 512);
    packw<<<512, 256, 0, stream>>>(fc1_w,  wFC1, 2048, 512);
    packw<<<512, 256, 0, stream>>>(fc2_w,  wFC2, 512, 2048);

    // LN1: x -> hA (bf16)
    ln_kernel<<<NTOK / 4, 256, 0, stream>>>(x, ln_g, ln_b, hA);
    // qkv = hA @ qkv_w^T  -> big
    gemm8p<0><<<dim3(6 * 256), 512, 0, stream>>>(
        hA, wQKV, NTOK, 1536, 512, 6, nullptr, nullptr, nullptr, big);
    // attention: big -> hA (o)
    attn_kernel<<<BQ, 256, 0, stream>>>(big, rpb, hA);
    // x1 = x + o @ proj_w^T + proj_b -> out (fp32)
    gemm8p<1><<<dim3(2 * 256), 512, 0, stream>>>(
        hA, wPROJ, NTOK, 512, 512, 2, proj_b, x, out, nullptr);
    // LN2: out -> hA (h2)
    ln_kernel<<<NTOK / 4, 256, 0, stream>>>(out, ln_g, ln_b, hA);
    // g = gelu(h2 @ fc1_w^T + fc1_b) -> big (bf16)
    gemm8p<2><<<dim3(8 * 256), 512, 0, stream>>>(
        hA, wFC1, NTOK, 2048, 512, 8, fc1_b, nullptr, nullptr, big);
    // out = x1 + g @ fc2_w^T + fc2_b (in-place residual read)
    gemm8p<1><<<dim3(2 * 256), 512, 0, stream>>>(
        big, wFC2, NTOK, 512, 2048, 2, fc2_b, out, out, nullptr);
}

// Round 9
// 844.805 us; speedup vs baseline: 1.0020x; 1.0020x over previous
//
#include <hip/hip_runtime.h>
#include <hip/hip_bf16.h>
#include <math.h>

// Problem constants
#define BQ   16384        // windows
#define CH   512
#define NH   8
#define HID  2048
#define NTOK (BQ*4)       // 65536 rows

using bf16 = __hip_bfloat16;
typedef __bf16 bf16x8 __attribute__((ext_vector_type(8)));
typedef float  f32x4  __attribute__((ext_vector_type(4)));

__device__ __forceinline__ void gload16(const void* g, void* l) {
    __builtin_amdgcn_global_load_lds(
        (const __attribute__((address_space(1))) void*)g,
        (__attribute__((address_space(3))) void*)l, 16, 0, 0);
}

// ---------------- weight pack: fp32 row-major [N][K] -> staged-order bf16 ----
// 8KB slab per (colblock cb of 128 rows-of-W, K-slice s of 32):
//   elem addr = (cb*NSk + s)*4096 + w*1024 + jj*512 + l*8      (w<4, jj<2, l<64)
//   content   = W[cb*128 + w*32 + jj*16 + (l>>2)][s*32 + ((l&3)^((l>>3)&3))*8 ..+8]
__global__ __launch_bounds__(256) void packw(const float* __restrict__ Wsrc,
                                             bf16* __restrict__ out, int N, int K) {
    int q = blockIdx.x * 256 + threadIdx.x;      // 16B-chunk id
    int NSk = K >> 5;
    int total = (N >> 7) * NSk * 512;
    if (q >= total) return;
    int l  = q & 63;
    int jj = (q >> 6) & 1;
    int w  = (q >> 7) & 3;
    int s  = (q >> 9) % NSk;
    int cb = q / (NSk * 512);
    int row = cb * 128 + w * 32 + jj * 16 + (l >> 2);
    int k   = s * 32 + ((l & 3) ^ ((l >> 3) & 3)) * 8;
    const float* src = Wsrc + (size_t)row * K + k;
    float4 v0 = *(const float4*)src;
    float4 v1 = *(const float4*)(src + 4);
    __align__(16) bf16 t[8];
    t[0] = __float2bfloat16(v0.x); t[1] = __float2bfloat16(v0.y);
    t[2] = __float2bfloat16(v0.z); t[3] = __float2bfloat16(v0.w);
    t[4] = __float2bfloat16(v1.x); t[5] = __float2bfloat16(v1.y);
    t[6] = __float2bfloat16(v1.z); t[7] = __float2bfloat16(v1.w);
    *(uint4*)&out[(size_t)q * 8] = *(const uint4*)t;
}

// ---------------- LayerNorm (fp32 in, bf16 out), one wave per row ----------------
__global__ __launch_bounds__(256) void ln_kernel(const float* __restrict__ x,
                                                 const float* __restrict__ g,
                                                 const float* __restrict__ b,
                                                 bf16* __restrict__ out) {
    int row  = blockIdx.x * 4 + (threadIdx.x >> 6);
    int lane = threadIdx.x & 63;
    const float* xr = x + (size_t)row * CH;
    int c0 = lane * 8;
    float4 v0 = *(const float4*)&xr[c0];
    float4 v1 = *(const float4*)&xr[c0 + 4];
    float s  = v0.x + v0.y + v0.z + v0.w + v1.x + v1.y + v1.z + v1.w;
    float sq = v0.x*v0.x + v0.y*v0.y + v0.z*v0.z + v0.w*v0.w
             + v1.x*v1.x + v1.y*v1.y + v1.z*v1.z + v1.w*v1.w;
#pragma unroll
    for (int off = 32; off >= 1; off >>= 1) {
        s  += __shfl_xor(s,  off, 64);
        sq += __shfl_xor(sq, off, 64);
    }
    float mu  = s * (1.0f / CH);
    float var = sq * (1.0f / CH) - mu * mu;
    float rs  = rsqrtf(var + 1e-5f);
    float4 g0 = *(const float4*)&g[c0];
    float4 g1 = *(const float4*)&g[c0 + 4];
    float4 b0 = *(const float4*)&b[c0];
    float4 b1 = *(const float4*)&b[c0 + 4];
    __align__(16) bf16 t[8];
    t[0] = __float2bfloat16((v0.x - mu) * rs * g0.x + b0.x);
    t[1] = __float2bfloat16((v0.y - mu) * rs * g0.y + b0.y);
    t[2] = __float2bfloat16((v0.z - mu) * rs * g0.z + b0.z);
    t[3] = __float2bfloat16((v0.w - mu) * rs * g0.w + b0.w);
    t[4] = __float2bfloat16((v1.x - mu) * rs * g1.x + b1.x);
    t[5] = __float2bfloat16((v1.y - mu) * rs * g1.y + b1.y);
    t[6] = __float2bfloat16((v1.z - mu) * rs * g1.z + b1.z);
    t[7] = __float2bfloat16((v1.w - mu) * rs * g1.w + b1.w);
    *(uint4*)&out[(size_t)row * CH + c0] = *(const uint4*)t;
}

// ---------------- GEMM 128x128, ring-3 LDS + counted vmcnt (R7 minus the drain) --
// C[M,N] = A[M,K] * B[N,K]^T, 4 waves (2x2), wave tile 64x64.
// Loop per K-32 slice s:  { vmcnt(4) ; s_barrier ; stage(s+2) ; compute(s) }
//  RAW: wave's own vmcnt(4) retires stage(s) (only stage(s+1) may remain);
//       the barrier then globalizes slot-s validity across waves.
//  WAR: stage(s+2) writes slot (s-1)%3, whose readers (compute(s-1)) completed
//       before this barrier by program order.
// ONE barrier per slice, vmcnt never 0 until the 2-iter peeled tail -> the
// m97-identified "vmcnt(0)+barrier drain" stall is gone; prefetch depth ~2
// slices covers HBM latency. LDS 48KB x 3 blocks/CU = 144KB <= 160.
// EPI 0: outB = bf16(acc); EPI 1: outF = acc+bias+resid; EPI 2: gelu -> outB.
template<int EPI>
__global__ __launch_bounds__(256, 3)
void gemm128(const bf16* __restrict__ A, const bf16* __restrict__ Bp,
             int M, int N, int K, int nbx,
             const float* __restrict__ bias,
             const float* resid, float* outF, bf16* __restrict__ outB) {
    __shared__ __align__(16) char lds[49152];
    const int tid  = threadIdx.x;
    const int w    = tid >> 6;     // wave 0..3
    const int lane = tid & 63;

    // bijective XCD swizzle (gridDim.x % 8 == 0 for all our shapes)
    const int nb  = gridDim.x;
    const int id  = blockIdx.x;
    const int swz = (id & 7) * (nb >> 3) + (id >> 3);
    const int bx  = swz % nbx, by = swz / nbx;
    const int bm = by * 128, bn = bx * 128;
    const int wrh = w >> 1;        // 0..1  (M half)
    const int wch = w & 1;         // 0..1  (N half)
    const int NSk = K >> 5;        // K/32 slices (>= 3)

    // A staging (strided rows, pre-swizzled k-part)
    const int rl  = lane >> 2;
    const int kpe = ((lane & 3) ^ ((lane >> 3) & 3)) * 8;
    const bf16* gA0 = A + (size_t)(bm + w * 32 + rl) * K + kpe;
    const bf16* gA1 = gA0 + (size_t)16 * K;
    // B staging (packed, contiguous 1KB per load)
    const bf16* gB = Bp + (size_t)(bn >> 7) * NSk * 4096 + w * 1024 + lane * 8;

    // fragment read offsets (bytes) within a slot; same XOR on the read side
    const int kslot = ((lane >> 4) ^ ((lane >> 1) & 3));
    const int aoff = (wrh * 64 + (lane & 15)) * 64 + kslot * 16;
    const int boff = 8192 + (wch * 64 + (lane & 15)) * 64 + kslot * 16;

    f32x4 acc[4][4] = {};

    auto stageTo = [&](int s, int slot) {
        char* base = (char*)lds + slot * 16384;
        gload16(gA0 + (size_t)s * 32,         base + w * 2048);
        gload16(gA1 + (size_t)s * 32,         base + w * 2048 + 1024);
        gload16(gB  + (size_t)s * 4096,       base + 8192 + w * 2048);
        gload16(gB  + (size_t)s * 4096 + 512, base + 8192 + w * 2048 + 1024);
    };

    auto compute = [&](int slot) {
        const char* base = (const char*)lds + slot * 16384;
        bf16x8 av[4], bv[4];
#pragma unroll
        for (int n = 0; n < 4; ++n)
            bv[n] = *(const bf16x8*)(base + boff + n * 1024);
#pragma unroll
        for (int m = 0; m < 4; ++m)
            av[m] = *(const bf16x8*)(base + aoff + m * 1024);
#pragma unroll
        for (int m = 0; m < 4; ++m)
#pragma unroll
            for (int n = 0; n < 4; ++n)
                acc[m][n] = __builtin_amdgcn_mfma_f32_16x16x32_bf16(av[m], bv[n], acc[m][n], 0, 0, 0);
    };

#define WAITV(n) asm volatile("s_waitcnt vmcnt(" #n ")" ::: "memory")

    stageTo(0, 0); stageTo(1, 1);
    int sc = 0, st = 2;            // sc = s%3 (compute), st = (s+2)%3 (stage)
    for (int s = 0; s < NSk - 2; ++s) {
        WAITV(4);
        __builtin_amdgcn_s_barrier();
        stageTo(s + 2, st);
        compute(sc);
        sc = (sc == 2) ? 0 : sc + 1;
        st = (st == 2) ? 0 : st + 1;
    }
    WAITV(4);
    __builtin_amdgcn_s_barrier();
    compute(sc);
    sc = (sc == 2) ? 0 : sc + 1;
    WAITV(0);
    __builtin_amdgcn_s_barrier();
    compute(sc);
#undef WAITV

    // epilogue: frag (m,n): row = wrh*64 + m*16 + (lane>>4)*4 + r, col = wch*64 + n*16 + (lane&15)
    const int erow0 = bm + wrh * 64 + (lane >> 4) * 4;
    const int ecol0 = bn + wch * 64 + (lane & 15);
#pragma unroll
    for (int m = 0; m < 4; ++m) {
#pragma unroll
        for (int n = 0; n < 4; ++n) {
            int col = ecol0 + n * 16;
#pragma unroll
            for (int r = 0; r < 4; ++r) {
                int row = erow0 + m * 16 + r;
                size_t idx = (size_t)row * N + col;
                float v = acc[m][n][r];
                if (EPI == 0) {
                    outB[idx] = __float2bfloat16(v);
                } else if (EPI == 1) {
                    outF[idx] = v + bias[col] + resid[idx];
                } else {
                    // tanh-form GELU (|err| vs exact erf-GELU ~3e-4 << bf16 ulp)
                    float t = v + bias[col];
                    float u = 0.7978845608f * t * (1.0f + 0.044715f * t * t);
                    float e = __expf(2.0f * u);
                    float th = 1.0f - 2.0f / (e + 1.0f);   // inf-safe
                    outB[idx] = __float2bfloat16(0.5f * t * (1.0f + th));
                }
            }
        }
    }
}

// ---------------- windowed attention: one block per window ----------------
__global__ __launch_bounds__(256)
void attn_kernel(const bf16* __restrict__ qkv, const float* __restrict__ rpb,
                 bf16* __restrict__ o) {
    __shared__ __align__(16) bf16 sT[4 * 1536];
    __shared__ float sS[NH][4][4];
    __shared__ float sP[NH][4][4];
    int b   = blockIdx.x;
    int tid = threadIdx.x;
    const bf16* src = qkv + (size_t)b * (4 * 1536);
#pragma unroll
    for (int it = 0; it < 3; ++it) {
        int e = (it * 256 + tid) * 8;
        *(uint4*)&sT[e] = *(const uint4*)&src[e];
    }
    __syncthreads();
    if (tid < 128) {
        int h = tid >> 4, i = (tid >> 2) & 3, j = tid & 3;
        const bf16* q = &sT[i * 1536 + h * 64];
        const bf16* k = &sT[j * 1536 + 512 + h * 64];
        float acc = 0.f;
#pragma unroll
        for (int d = 0; d < 64; ++d)
            acc += __bfloat162float(q[d]) * __bfloat162float(k[d]);
        int rel = (((i >> 1) - (j >> 1)) + 1) * 3 + (((i & 1) - (j & 1)) + 1);
        sS[h][i][j] = acc * 0.125f + rpb[rel * NH + h];
    }
    __syncthreads();
    if (tid < 32) {
        int h = tid >> 2, i = tid & 3;
        float s0 = sS[h][i][0], s1 = sS[h][i][1], s2 = sS[h][i][2], s3 = sS[h][i][3];
        float mx = fmaxf(fmaxf(s0, s1), fmaxf(s2, s3));
        float e0 = expf(s0 - mx), e1 = expf(s1 - mx), e2 = expf(s2 - mx), e3 = expf(s3 - mx);
        float inv = 1.f / (e0 + e1 + e2 + e3);
        sP[h][i][0] = e0 * inv; sP[h][i][1] = e1 * inv;
        sP[h][i][2] = e2 * inv; sP[h][i][3] = e3 * inv;
    }
    __syncthreads();
    {
        int h = tid >> 5, tl = tid & 31;
        int d = tl * 2;
        const bf16* v = &sT[1024 + h * 64 + d];
#pragma unroll
        for (int i = 0; i < 4; ++i) {
            float p0 = sP[h][i][0], p1 = sP[h][i][1], p2 = sP[h][i][2], p3 = sP[h][i][3];
            float o0 = p0 * __bfloat162float(v[0])        + p1 * __bfloat162float(v[1536])
                     + p2 * __bfloat162float(v[2 * 1536]) + p3 * __bfloat162float(v[3 * 1536]);
            float o1 = p0 * __bfloat162float(v[1])            + p1 * __bfloat162float(v[1536 + 1])
                     + p2 * __bfloat162float(v[2 * 1536 + 1]) + p3 * __bfloat162float(v[3 * 1536 + 1]);
            __hip_bfloat162 pr;
            pr.x = __float2bfloat16(o0);
            pr.y = __float2bfloat16(o1);
            *(__hip_bfloat162*)&o[(size_t)(b * 4 + i) * CH + h * 64 + d] = pr;
        }
    }
}

extern "C" void kernel_launch(void* const* d_in, const int* in_sizes, int n_in,
                              void* d_out, int out_size, void* d_ws, size_t ws_size,
                              hipStream_t stream) {
    const float* x      = (const float*)d_in[0];
    const float* ln_g   = (const float*)d_in[1];
    const float* ln_b   = (const float*)d_in[2];
    const float* qkv_w  = (const float*)d_in[3];
    const float* proj_w = (const float*)d_in[4];
    const float* proj_b = (const float*)d_in[5];
    const float* rpb    = (const float*)d_in[6];
    const float* fc1_w  = (const float*)d_in[7];
    const float* fc1_b  = (const float*)d_in[8];
    const float* fc2_w  = (const float*)d_in[9];
    const float* fc2_b  = (const float*)d_in[10];
    float* out = (float*)d_out;

    // workspace layout (16B aligned throughout)
    char* ws = (char*)d_ws;
    bf16* wQKV  = (bf16*)ws;  ws += (size_t)1536 * 512 * 2;   // packed
    bf16* wPROJ = (bf16*)ws;  ws += (size_t)512  * 512 * 2;
    bf16* wFC1  = (bf16*)ws;  ws += (size_t)2048 * 512 * 2;
    bf16* wFC2  = (bf16*)ws;  ws += (size_t)512 * 2048 * 2;
    bf16* hA    = (bf16*)ws;  ws += (size_t)NTOK * 512 * 2;   // 64 MB: h_ln -> o -> h2
    bf16* big   = (bf16*)ws;                                  // 256 MB: qkv -> fc1 out
    const size_t needed = 6291456ull + 67108864ull + 268435456ull;
    if (ws_size < needed) return;

    // weight packing (fp32 -> staged-order bf16, 128-row col-blocks)
    packw<<<384, 256, 0, stream>>>(qkv_w,  wQKV, 1536, 512);
    packw<<<128, 256, 0, stream>>>(proj_w, wPROJ, 512, 512);
    packw<<<512, 256, 0, stream>>>(fc1_w,  wFC1, 2048, 512);
    packw<<<512, 256, 0, stream>>>(fc2_w,  wFC2, 512, 2048);

    // LN1: x -> hA (bf16)
    ln_kernel<<<NTOK / 4, 256, 0, stream>>>(x, ln_g, ln_b, hA);
    // qkv = hA @ qkv_w^T  -> big
    gemm128<0><<<dim3(12 * 512), 256, 0, stream>>>(
        hA, wQKV, NTOK, 1536, 512, 12, nullptr, nullptr, nullptr, big);
    // attention: big -> hA (o)
    attn_kernel<<<BQ, 256, 0, stream>>>(big, rpb, hA);
    // x1 = x + o @ proj_w^T + proj_b -> out (fp32)
    gemm128<1><<<dim3(4 * 512), 256, 0, stream>>>(
        hA, wPROJ, NTOK, 512, 512, 4, proj_b, x, out, nullptr);
    // LN2: out -> hA (h2)
    ln_kernel<<<NTOK / 4, 256, 0, stream>>>(out, ln_g, ln_b, hA);
    // g = gelu(h2 @ fc1_w^T + fc1_b) -> big (bf16)
    gemm128<2><<<dim3(16 * 512), 256, 0, stream>>>(
        hA, wFC1, NTOK, 2048, 512, 16, fc1_b, nullptr, nullptr, big);
    // out = x1 + g @ fc2_w^T + fc2_b (in-place residual read)
    gemm128<1><<<dim3(4 * 512), 256, 0, stream>>>(
        big, wFC2, NTOK, 512, 2048, 4, fc2_b, out, out, nullptr);
}

// Round 10
// 804.423 us; speedup vs baseline: 1.0523x; 1.0502x over previous
//
#include <hip/hip_runtime.h>
#include <hip/hip_bf16.h>
#include <math.h>

// Problem constants
#define BQ   16384        // windows
#define CH   512
#define NH   8
#define HID  2048
#define NTOK (BQ*4)       // 65536 rows

using bf16 = __hip_bfloat16;
typedef __bf16 bf16x8 __attribute__((ext_vector_type(8)));
typedef float  f32x4  __attribute__((ext_vector_type(4)));

#define FENCE() asm volatile("" ::: "memory")

__device__ __forceinline__ void gload16(const void* g, void* l) {
    __builtin_amdgcn_global_load_lds(
        (const __attribute__((address_space(1))) void*)g,
        (__attribute__((address_space(3))) void*)l, 16, 0, 0);
}

// ---------------- weight pack: fp32 row-major [N][K] -> staged-order bf16 ----
// 8KB slab per (colblock cb of 128 rows-of-W, K-slice s of 32):
//   elem addr = (cb*NSk + s)*4096 + w*1024 + jj*512 + l*8      (w<4, jj<2, l<64)
//   content   = W[cb*128 + w*32 + jj*16 + (l>>2)][s*32 + ((l&3)^((l>>3)&3))*8 ..+8]
__global__ __launch_bounds__(256) void packw(const float* __restrict__ Wsrc,
                                             bf16* __restrict__ out, int N, int K) {
    int q = blockIdx.x * 256 + threadIdx.x;      // 16B-chunk id
    int NSk = K >> 5;
    int total = (N >> 7) * NSk * 512;
    if (q >= total) return;
    int l  = q & 63;
    int jj = (q >> 6) & 1;
    int w  = (q >> 7) & 3;
    int s  = (q >> 9) % NSk;
    int cb = q / (NSk * 512);
    int row = cb * 128 + w * 32 + jj * 16 + (l >> 2);
    int k   = s * 32 + ((l & 3) ^ ((l >> 3) & 3)) * 8;
    const float* src = Wsrc + (size_t)row * K + k;
    float4 v0 = *(const float4*)src;
    float4 v1 = *(const float4*)(src + 4);
    __align__(16) bf16 t[8];
    t[0] = __float2bfloat16(v0.x); t[1] = __float2bfloat16(v0.y);
    t[2] = __float2bfloat16(v0.z); t[3] = __float2bfloat16(v0.w);
    t[4] = __float2bfloat16(v1.x); t[5] = __float2bfloat16(v1.y);
    t[6] = __float2bfloat16(v1.z); t[7] = __float2bfloat16(v1.w);
    *(uint4*)&out[(size_t)q * 8] = *(const uint4*)t;
}

// ---------------- LayerNorm (fp32 in, bf16 out), one wave per row ----------------
__global__ __launch_bounds__(256) void ln_kernel(const float* __restrict__ x,
                                                 const float* __restrict__ g,
                                                 const float* __restrict__ b,
                                                 bf16* __restrict__ out) {
    int row  = blockIdx.x * 4 + (threadIdx.x >> 6);
    int lane = threadIdx.x & 63;
    const float* xr = x + (size_t)row * CH;
    int c0 = lane * 8;
    float4 v0 = *(const float4*)&xr[c0];
    float4 v1 = *(const float4*)&xr[c0 + 4];
    float s  = v0.x + v0.y + v0.z + v0.w + v1.x + v1.y + v1.z + v1.w;
    float sq = v0.x*v0.x + v0.y*v0.y + v0.z*v0.z + v0.w*v0.w
             + v1.x*v1.x + v1.y*v1.y + v1.z*v1.z + v1.w*v1.w;
#pragma unroll
    for (int off = 32; off >= 1; off >>= 1) {
        s  += __shfl_xor(s,  off, 64);
        sq += __shfl_xor(sq, off, 64);
    }
    float mu  = s * (1.0f / CH);
    float var = sq * (1.0f / CH) - mu * mu;
    float rs  = rsqrtf(var + 1e-5f);
    float4 g0 = *(const float4*)&g[c0];
    float4 g1 = *(const float4*)&g[c0 + 4];
    float4 b0 = *(const float4*)&b[c0];
    float4 b1 = *(const float4*)&b[c0 + 4];
    __align__(16) bf16 t[8];
    t[0] = __float2bfloat16((v0.x - mu) * rs * g0.x + b0.x);
    t[1] = __float2bfloat16((v0.y - mu) * rs * g0.y + b0.y);
    t[2] = __float2bfloat16((v0.z - mu) * rs * g0.z + b0.z);
    t[3] = __float2bfloat16((v0.w - mu) * rs * g0.w + b0.w);
    t[4] = __float2bfloat16((v1.x - mu) * rs * g1.x + b1.x);
    t[5] = __float2bfloat16((v1.y - mu) * rs * g1.y + b1.y);
    t[6] = __float2bfloat16((v1.z - mu) * rs * g1.z + b1.z);
    t[7] = __float2bfloat16((v1.w - mu) * rs * g1.w + b1.w);
    *(uint4*)&out[(size_t)row * CH + c0] = *(const uint4*)t;
}

// ---------------- GEMM 128x128, ring-2 + counted vmcnt (R7 minus the drain) ----
// C[M,N] = A[M,K] * B[N,K]^T, 4 waves (2x2), wave tile 64x64.
// Loop per K-32 slice s:
//   stage(s+1) ; vmcnt(4) ; s_barrier ; compute(s) ; s_barrier
//  RAW: own vmcnt(4) retires stage(s) (only stage(s+1)'s 4 loads remain);
//       the first barrier then globalizes slot-s validity across waves.
//  WAR: second barrier ensures all waves' compute(s) ds_reads are COMPLETE
//       (their MFMA lgkm deps force completion) before any wave's next-iter
//       stage(s+2) rewrites slot s&1.
// Same 32KB LDS as R7 (occupancy ~4 blocks/CU preserved); the just-issued
// stage loads are NOT drained (R7's __syncthreads vmcnt(0) stall removed) --
// they ride across the compute phase. 2 cheap barriers/slice.
// EPI 0: outB = bf16(acc); EPI 1: outF = acc+bias+resid; EPI 2: gelu -> outB.
template<int EPI>
__global__ __launch_bounds__(256, 3)
void gemm128(const bf16* __restrict__ A, const bf16* __restrict__ Bp,
             int M, int N, int K, int nbx,
             const float* __restrict__ bias,
             const float* resid, float* outF, bf16* __restrict__ outB) {
    __shared__ __align__(16) char lds[32768];
    const int tid  = threadIdx.x;
    const int w    = tid >> 6;     // wave 0..3
    const int lane = tid & 63;

    // bijective XCD swizzle (gridDim.x % 8 == 0 for all our shapes)
    const int nb  = gridDim.x;
    const int id  = blockIdx.x;
    const int swz = (id & 7) * (nb >> 3) + (id >> 3);
    const int bx  = swz % nbx, by = swz / nbx;
    const int bm = by * 128, bn = bx * 128;
    const int wrh = w >> 1;        // 0..1  (M half)
    const int wch = w & 1;         // 0..1  (N half)
    const int NSk = K >> 5;        // K/32 slices (>= 2)

    // A staging (strided rows, pre-swizzled k-part)
    const int rl  = lane >> 2;
    const int kpe = ((lane & 3) ^ ((lane >> 3) & 3)) * 8;
    const bf16* gA0 = A + (size_t)(bm + w * 32 + rl) * K + kpe;
    const bf16* gA1 = gA0 + (size_t)16 * K;
    // B staging (packed, contiguous 1KB per load)
    const bf16* gB = Bp + (size_t)(bn >> 7) * NSk * 4096 + w * 1024 + lane * 8;

    // fragment read offsets (bytes) within a slot; same XOR on the read side
    const int kslot = ((lane >> 4) ^ ((lane >> 1) & 3));
    const int aoff = (wrh * 64 + (lane & 15)) * 64 + kslot * 16;
    const int boff = 8192 + (wch * 64 + (lane & 15)) * 64 + kslot * 16;

    f32x4 acc[4][4] = {};

    auto stage = [&](int s) {
        char* base = (char*)lds + (s & 1) * 16384;
        gload16(gA0 + (size_t)s * 32,         base + w * 2048);
        gload16(gA1 + (size_t)s * 32,         base + w * 2048 + 1024);
        gload16(gB  + (size_t)s * 4096,       base + 8192 + w * 2048);
        gload16(gB  + (size_t)s * 4096 + 512, base + 8192 + w * 2048 + 1024);
    };

    auto compute = [&](int slot) {
        const char* base = (const char*)lds + slot * 16384;
        bf16x8 av[4], bv[4];
#pragma unroll
        for (int n = 0; n < 4; ++n)
            bv[n] = *(const bf16x8*)(base + boff + n * 1024);
#pragma unroll
        for (int m = 0; m < 4; ++m)
            av[m] = *(const bf16x8*)(base + aoff + m * 1024);
#pragma unroll
        for (int m = 0; m < 4; ++m)
#pragma unroll
            for (int n = 0; n < 4; ++n)
                acc[m][n] = __builtin_amdgcn_mfma_f32_16x16x32_bf16(av[m], bv[n], acc[m][n], 0, 0, 0);
    };

#define WAITV(n) asm volatile("s_waitcnt vmcnt(" #n ")" ::: "memory")

    stage(0);
    for (int s = 0; s < NSk - 1; ++s) {
        stage(s + 1);
        WAITV(4);                       // own stage(s) landed; stage(s+1) in flight
        __builtin_amdgcn_s_barrier();   // globalize slot-s validity
        FENCE();
        compute(s & 1);
        FENCE();
        __builtin_amdgcn_s_barrier();   // all reads of slot s&1 done before rewrite
    }
    WAITV(0);                           // final slice's loads landed
    __builtin_amdgcn_s_barrier();
    FENCE();
    compute((NSk - 1) & 1);
#undef WAITV

    // epilogue: frag (m,n): row = wrh*64 + m*16 + (lane>>4)*4 + r, col = wch*64 + n*16 + (lane&15)
    const int erow0 = bm + wrh * 64 + (lane >> 4) * 4;
    const int ecol0 = bn + wch * 64 + (lane & 15);
#pragma unroll
    for (int m = 0; m < 4; ++m) {
#pragma unroll
        for (int n = 0; n < 4; ++n) {
            int col = ecol0 + n * 16;
#pragma unroll
            for (int r = 0; r < 4; ++r) {
                int row = erow0 + m * 16 + r;
                size_t idx = (size_t)row * N + col;
                float v = acc[m][n][r];
                if (EPI == 0) {
                    outB[idx] = __float2bfloat16(v);
                } else if (EPI == 1) {
                    outF[idx] = v + bias[col] + resid[idx];
                } else {
                    // tanh-form GELU (|err| vs exact erf-GELU ~3e-4 << bf16 ulp)
                    float t = v + bias[col];
                    float u = 0.7978845608f * t * (1.0f + 0.044715f * t * t);
                    float e = __expf(2.0f * u);
                    float th = 1.0f - 2.0f / (e + 1.0f);   // inf-safe
                    outB[idx] = __float2bfloat16(0.5f * t * (1.0f + th));
                }
            }
        }
    }
}

// ---------------- windowed attention: one block per window ----------------
__global__ __launch_bounds__(256)
void attn_kernel(const bf16* __restrict__ qkv, const float* __restrict__ rpb,
                 bf16* __restrict__ o) {
    __shared__ __align__(16) bf16 sT[4 * 1536];
    __shared__ float sS[NH][4][4];
    __shared__ float sP[NH][4][4];
    int b   = blockIdx.x;
    int tid = threadIdx.x;
    const bf16* src = qkv + (size_t)b * (4 * 1536);
#pragma unroll
    for (int it = 0; it < 3; ++it) {
        int e = (it * 256 + tid) * 8;
        *(uint4*)&sT[e] = *(const uint4*)&src[e];
    }
    __syncthreads();
    if (tid < 128) {
        int h = tid >> 4, i = (tid >> 2) & 3, j = tid & 3;
        const bf16* q = &sT[i * 1536 + h * 64];
        const bf16* k = &sT[j * 1536 + 512 + h * 64];
        float acc = 0.f;
#pragma unroll
        for (int d = 0; d < 64; ++d)
            acc += __bfloat162float(q[d]) * __bfloat162float(k[d]);
        int rel = (((i >> 1) - (j >> 1)) + 1) * 3 + (((i & 1) - (j & 1)) + 1);
        sS[h][i][j] = acc * 0.125f + rpb[rel * NH + h];
    }
    __syncthreads();
    if (tid < 32) {
        int h = tid >> 2, i = tid & 3;
        float s0 = sS[h][i][0], s1 = sS[h][i][1], s2 = sS[h][i][2], s3 = sS[h][i][3];
        float mx = fmaxf(fmaxf(s0, s1), fmaxf(s2, s3));
        float e0 = expf(s0 - mx), e1 = expf(s1 - mx), e2 = expf(s2 - mx), e3 = expf(s3 - mx);
        float inv = 1.f / (e0 + e1 + e2 + e3);
        sP[h][i][0] = e0 * inv; sP[h][i][1] = e1 * inv;
        sP[h][i][2] = e2 * inv; sP[h][i][3] = e3 * inv;
    }
    __syncthreads();
    {
        int h = tid >> 5, tl = tid & 31;
        int d = tl * 2;
        const bf16* v = &sT[1024 + h * 64 + d];
#pragma unroll
        for (int i = 0; i < 4; ++i) {
            float p0 = sP[h][i][0], p1 = sP[h][i][1], p2 = sP[h][i][2], p3 = sP[h][i][3];
            float o0 = p0 * __bfloat162float(v[0])        + p1 * __bfloat162float(v[1536])
                     + p2 * __bfloat162float(v[2 * 1536]) + p3 * __bfloat162float(v[3 * 1536]);
            float o1 = p0 * __bfloat162float(v[1])            + p1 * __bfloat162float(v[1536 + 1])
                     + p2 * __bfloat162float(v[2 * 1536 + 1]) + p3 * __bfloat162float(v[3 * 1536 + 1]);
            __hip_bfloat162 pr;
            pr.x = __float2bfloat16(o0);
            pr.y = __float2bfloat16(o1);
            *(__hip_bfloat162*)&o[(size_t)(b * 4 + i) * CH + h * 64 + d] = pr;
        }
    }
}

extern "C" void kernel_launch(void* const* d_in, const int* in_sizes, int n_in,
                              void* d_out, int out_size, void* d_ws, size_t ws_size,
                              hipStream_t stream) {
    const float* x      = (const float*)d_in[0];
    const float* ln_g   = (const float*)d_in[1];
    const float* ln_b   = (const float*)d_in[2];
    const float* qkv_w  = (const float*)d_in[3];
    const float* proj_w = (const float*)d_in[4];
    const float* proj_b = (const float*)d_in[5];
    const float* rpb    = (const float*)d_in[6];
    const float* fc1_w  = (const float*)d_in[7];
    const float* fc1_b  = (const float*)d_in[8];
    const float* fc2_w  = (const float*)d_in[9];
    const float* fc2_b  = (const float*)d_in[10];
    float* out = (float*)d_out;

    // workspace layout (16B aligned throughout)
    char* ws = (char*)d_ws;
    bf16* wQKV  = (bf16*)ws;  ws += (size_t)1536 * 512 * 2;   // packed
    bf16* wPROJ = (bf16*)ws;  ws += (size_t)512  * 512 * 2;
    bf16* wFC1  = (bf16*)ws;  ws += (size_t)2048 * 512 * 2;
    bf16* wFC2  = (bf16*)ws;  ws += (size_t)512 * 2048 * 2;
    bf16* hA    = (bf16*)ws;  ws += (size_t)NTOK * 512 * 2;   // 64 MB: h_ln -> o -> h2
    bf16* big   = (bf16*)ws;                                  // 256 MB: qkv -> fc1 out
    const size_t needed = 6291456ull + 67108864ull + 268435456ull;
    if (ws_size < needed) return;

    // weight packing (fp32 -> staged-order bf16, 128-row col-blocks)
    packw<<<384, 256, 0, stream>>>(qkv_w,  wQKV, 1536, 512);
    packw<<<128, 256, 0, stream>>>(proj_w, wPROJ, 512, 512);
    packw<<<512, 256, 0, stream>>>(fc1_w,  wFC1, 2048, 512);
    packw<<<512, 256, 0, stream>>>(fc2_w,  wFC2, 512, 2048);

    // LN1: x -> hA (bf16)
    ln_kernel<<<NTOK / 4, 256, 0, stream>>>(x, ln_g, ln_b, hA);
    // qkv = hA @ qkv_w^T  -> big
    gemm128<0><<<dim3(12 * 512), 256, 0, stream>>>(
        hA, wQKV, NTOK, 1536, 512, 12, nullptr, nullptr, nullptr, big);
    // attention: big -> hA (o)
    attn_kernel<<<BQ, 256, 0, stream>>>(big, rpb, hA);
    // x1 = x + o @ proj_w^T + proj_b -> out (fp32)
    gemm128<1><<<dim3(4 * 512), 256, 0, stream>>>(
        hA, wPROJ, NTOK, 512, 512, 4, proj_b, x, out, nullptr);
    // LN2: out -> hA (h2)
    ln_kernel<<<NTOK / 4, 256, 0, stream>>>(out, ln_g, ln_b, hA);
    // g = gelu(h2 @ fc1_w^T + fc1_b) -> big (bf16)
    gemm128<2><<<dim3(16 * 512), 256, 0, stream>>>(
        hA, wFC1, NTOK, 2048, 512, 16, fc1_b, nullptr, nullptr, big);
    // out = x1 + g @ fc2_w^T + fc2_b (in-place residual read)
    gemm128<1><<<dim3(4 * 512), 256, 0, stream>>>(
        big, wFC2, NTOK, 512, 2048, 4, fc2_b, out, out, nullptr);
}